// Round 7
// baseline (495.973 us; speedup 1.0000x reference)
//
#include <hip/hip_runtime.h>
#include <math.h>

#define NEG_SLOPE 0.2f
#define BN_EPS 1e-5f

// ---------- helpers ----------

__device__ __forceinline__ void edge_sd(const int* __restrict__ ei, int E, int eid, int& s, int& d) {
    if (eid < E) { s = ei[eid]; d = ei[E + eid]; }
    else         { s = d = eid - E; }   // self-loops appended after the E real edges
}

__device__ __forceinline__ float lrelu(float v) { return v > 0.f ? v : NEG_SLOPE * v; }

// round-to-nearest-even fp32 -> bf16 bits
__device__ __forceinline__ unsigned short f2bf(float f) {
    unsigned u = __float_as_uint(f);
    u += 0x7fffu + ((u >> 16) & 1u);
    return (unsigned short)(u >> 16);
}

// ---------- W transpose: Wt[col][k] = W[k][col], for both layers (once) ----------
__global__ __launch_bounds__(256) void transpose_kernel(const float* __restrict__ W0,
                                                        const float* __restrict__ W1,
                                                        float* __restrict__ T0,
                                                        float* __restrict__ T1) {
    int b = blockIdx.x;
    const float* S = (b & 4) ? W1 : W0;
    float*       T = (b & 4) ? T1 : T0;
    int part = b & 3;
    for (int i = threadIdx.x; i < 4096; i += 256) {
        int idx = part * 4096 + i;
        T[(idx & 127) * 128 + (idx >> 7)] = S[idx];
    }
}

// ---------- GEMM: act(X)[N,128] @ W[128,128] -> bf16 shadow + fused attention logits ----------
// Structure (r6 post-mortem): the old col-quad layout made every wave re-read the full
// 2KB W k4-slice from LDS -> LDS pipe 3x oversubscribed (VALU:LDS inst ratio 8:1, need
// >=24:1). Now: lane = row, each wave owns 8 COLUMNS; W comes as 8 wave-uniform float4
// broadcast loads from transposed Wt (no LDS, L1/L2-resident); X is 1 swizzled
// ds_read_b128 per lane per k4 -> 1 LDS inst per 32 FMA insts. k ascending per output
// -> GEMM results bitwise identical to previous rounds.
// If bnmu != nullptr, applies BN+ELU to X elements while staging into LDS.
__global__ __launch_bounds__(256) void gemm128(const float* __restrict__ X,
                                               const float* __restrict__ Wt,
                                               unsigned short* __restrict__ Ybf,
                                               const float* __restrict__ att_s,
                                               const float* __restrict__ att_d,
                                               float* __restrict__ a_srcO,
                                               float* __restrict__ a_dstO,
                                               const float* __restrict__ bnmu,
                                               const float* __restrict__ bnrs,
                                               const float* __restrict__ gamma,
                                               const float* __restrict__ beta,
                                               int Nrows) {
    __shared__ float xs[64 * 128];     // 32 KB X tile, row-swizzled
    int bm = blockIdx.x * 64;
    int cg = blockIdx.y;               // column group: global cols cg*32 .. cg*32+31
    int tid = threadIdx.x;

    const float4* Xv = (const float4*)(X + (size_t)bm * 128);
    float4* xsv = (float4*)xs;
    if (bnmu == nullptr) {
        for (int i = tid; i < 2048; i += 256) {
            int row = i >> 5, c = i & 31;
            float4 v = (bm + row < Nrows) ? Xv[i] : make_float4(0.f, 0.f, 0.f, 0.f);
            xsv[((row << 5) | c) ^ (row & 7)] = v;     // G4 XOR swizzle
        }
    } else {
        for (int i = tid; i < 2048; i += 256) {
            int row = i >> 5, c = i & 31;
            int cb = c * 4;
            float4 v = (bm + row < Nrows) ? Xv[i] : make_float4(0.f, 0.f, 0.f, 0.f);
            float4 m4 = *(const float4*)(bnmu + cb);
            float4 r4 = *(const float4*)(bnrs + cb);
            float4 g4 = *(const float4*)(gamma + cb);
            float4 b4 = *(const float4*)(beta + cb);
            v.x = (v.x - m4.x) * r4.x * g4.x + b4.x;
            v.y = (v.y - m4.y) * r4.y * g4.y + b4.y;
            v.z = (v.z - m4.z) * r4.z * g4.z + b4.z;
            v.w = (v.w - m4.w) * r4.w * g4.w + b4.w;
            v.x = v.x > 0.f ? v.x : expm1f(v.x);
            v.y = v.y > 0.f ? v.y : expm1f(v.y);
            v.z = v.z > 0.f ? v.z : expm1f(v.z);
            v.w = v.w > 0.f ? v.w : expm1f(v.w);
            xsv[((row << 5) | c) ^ (row & 7)] = v;
        }
    }
    __syncthreads();

    int w = tid >> 6;          // wave 0..3 -> owns cols c0..c0+7
    int lane = tid & 63;       // lane = row within tile
    int c0 = cg * 32 + w * 8;

    float acc[8];
#pragma unroll
    for (int j = 0; j < 8; j++) acc[j] = 0.f;

    const float4* xr = (const float4*)xs;
    const float* wbase = Wt + (size_t)c0 * 128;

#pragma unroll 2
    for (int k4 = 0; k4 < 32; k4++) {
        float4 x4 = xr[((lane << 5) | k4) ^ (lane & 7)];   // ds_read_b128, conflict-free
#pragma unroll
        for (int j = 0; j < 8; j++) {
            float4 wj = *(const float4*)(wbase + j * 128 + k4 * 4);  // wave-uniform broadcast
            acc[j] += x4.x * wj.x;
            acc[j] += x4.y * wj.y;
            acc[j] += x4.z * wj.z;
            acc[j] += x4.w * wj.w;
        }
    }

    // ---- epilogue: attention logits (cross-wave pair reduce) + bf16 out via LDS ----
    __syncthreads();                                   // xs free now
    float* sred = xs;                                  // [4 waves][64 rows][2]
    unsigned short* outls = (unsigned short*)(xs + 512);  // [64 rows][32 cols]

    int h = cg * 2 + (w >> 1);                         // head for this wave pair
    int ao = (w & 1) * 8;                              // col offset within head
    float4 asl = *(const float4*)(att_s + h * 16 + ao);
    float4 ash = *(const float4*)(att_s + h * 16 + ao + 4);
    float4 adl = *(const float4*)(att_d + h * 16 + ao);
    float4 adh = *(const float4*)(att_d + h * 16 + ao + 4);
    float ps = acc[0] * asl.x + acc[1] * asl.y + acc[2] * asl.z + acc[3] * asl.w
             + acc[4] * ash.x + acc[5] * ash.y + acc[6] * ash.z + acc[7] * ash.w;
    float pd = acc[0] * adl.x + acc[1] * adl.y + acc[2] * adl.z + acc[3] * adl.w
             + acc[4] * adh.x + acc[5] * adh.y + acc[6] * adh.z + acc[7] * adh.w;
    sred[(w * 64 + lane) * 2]     = ps;
    sred[(w * 64 + lane) * 2 + 1] = pd;

    ushort4 p0, p1;
    p0.x = f2bf(acc[0]); p0.y = f2bf(acc[1]); p0.z = f2bf(acc[2]); p0.w = f2bf(acc[3]);
    p1.x = f2bf(acc[4]); p1.y = f2bf(acc[5]); p1.z = f2bf(acc[6]); p1.w = f2bf(acc[7]);
    *(ushort4*)(outls + lane * 32 + w * 8)     = p0;
    *(ushort4*)(outls + lane * 32 + w * 8 + 4) = p1;
    __syncthreads();

    if (tid < 128) {
        int r = tid & 63, p = tid >> 6;
        if (bm + r < Nrows) {
            float s0 = sred[((2 * p) * 64 + r) * 2]     + sred[((2 * p + 1) * 64 + r) * 2];
            float d0 = sred[((2 * p) * 64 + r) * 2 + 1] + sred[((2 * p + 1) * 64 + r) * 2 + 1];
            int hh = cg * 2 + p;
            a_srcO[(size_t)(bm + r) * 8 + hh] = s0;
            a_dstO[(size_t)(bm + r) * 8 + hh] = d0;
        }
    }
    {
        int r = tid >> 2, ch = tid & 3;                // 256 threads copy 256x16B
        if (bm + r < Nrows) {
            uint4 v = *(uint4*)(outls + r * 32 + ch * 8);
            *(uint4*)(Ybf + (size_t)(bm + r) * 128 + cg * 32 + ch * 8) = v;
        }
    }
}

// ---------- CSR build: histogram of dst + within-bucket rank (atomic return value) ----------
__global__ void hist_kernel(const int* __restrict__ ei, int E, int Etot,
                            int* __restrict__ counts, int* __restrict__ rank) {
    int eid = blockIdx.x * 256 + threadIdx.x;
    if (eid >= Etot) return;
    int s, d;
    edge_sd(ei, E, eid, s, d);
    rank[eid] = atomicAdd(&counts[d], 1);
}

// ---------- CSR build: parallel 3-stage exclusive scan ----------
__global__ __launch_bounds__(256) void chunksum_kernel(const int* __restrict__ counts,
                                                       int* __restrict__ csum, int N) {
    __shared__ int red[256];
    int base = blockIdx.x * 1024;
    int s = 0;
    for (int i = threadIdx.x; i < 1024; i += 256) {
        int idx = base + i;
        s += (idx < N) ? counts[idx] : 0;
    }
    red[threadIdx.x] = s;
    __syncthreads();
#pragma unroll
    for (int st = 128; st > 0; st >>= 1) {
        if (threadIdx.x < st) red[threadIdx.x] += red[threadIdx.x + st];
        __syncthreads();
    }
    if (threadIdx.x == 0) csum[blockIdx.x] = red[0];
}

__global__ void chunkscan_kernel(int* __restrict__ csum, int nchunk) {
    int lane = threadIdx.x;
    int v = (lane < nchunk) ? csum[lane] : 0;
    int incl = v;
#pragma unroll
    for (int off = 1; off < 64; off <<= 1) {
        int t = __shfl_up(incl, off);
        if (lane >= off) incl += t;
    }
    if (lane < nchunk) csum[lane] = incl - v;
}

__global__ __launch_bounds__(1024) void scanfinal_kernel(const int* __restrict__ counts,
                                                         const int* __restrict__ csum,
                                                         int* __restrict__ rowptr, int N) {
    __shared__ int wsum[16], woff_s[16];
    int tid = threadIdx.x, lane = tid & 63, wid = tid >> 6;
    int idx = blockIdx.x * 1024 + tid;
    int v = (idx < N) ? counts[idx] : 0;
    int incl = v;
#pragma unroll
    for (int off = 1; off < 64; off <<= 1) {
        int t = __shfl_up(incl, off);
        if (lane >= off) incl += t;
    }
    if (lane == 63) wsum[wid] = incl;
    __syncthreads();
    if (wid == 0 && lane < 16) {
        int w = wsum[lane], iw = w;
#pragma unroll
        for (int off = 1; off < 16; off <<= 1) {
            int t = __shfl_up(iw, off);
            if (lane >= off) iw += t;
        }
        woff_s[lane] = iw - w;
    }
    __syncthreads();
    if (idx < N) rowptr[idx + 1] = csum[blockIdx.x] + woff_s[wid] + incl;
    if (blockIdx.x == 0 && tid == 0) rowptr[0] = 0;
}

// ---------- CSR build: scatter src ids (NO atomics; rank precomputed in hist) ----------
__global__ void scatter_kernel(const int* __restrict__ ei, int E, int Etot,
                               const int* __restrict__ rowptr, const int* __restrict__ rank,
                               unsigned short* __restrict__ ssrc) {
    int eid = blockIdx.x * 256 + threadIdx.x;
    if (eid >= Etot) return;
    int s, d;
    edge_sd(ei, E, eid, s, d);
    ssrc[rowptr[d] + rank[eid]] = (unsigned short)s;
}

// ---------- fused softmax + aggregation: one wave per dst, 8 edges per iteration ----------
// Software-pipelined: row-gathers issued before exp/bpermute; next batch's ssrc/a_src
// prefetched during the FMA phase (breaks the serial load->exp->shuffle->load chain).
// MEAN=false: writes full [dst,128]. MEAN=true: head-mean fused -> writes [dst,16].
template <bool MEAN>
__global__ __launch_bounds__(256) void agg_kernel(const int* __restrict__ rowptr,
                                                  const unsigned short* __restrict__ ssrc,
                                                  const float* __restrict__ a_src,
                                                  const float* __restrict__ a_dst,
                                                  const unsigned short* __restrict__ Hbf,
                                                  float* __restrict__ outbuf, int N) {
    int wid = threadIdx.x >> 6;
    int dst = blockIdx.x * 4 + wid;
    if (dst >= N) return;
    int lane = threadIdx.x & 63;
    int j  = lane >> 3;      // edge slot 0..7 (exp phase)
    int hj = lane & 7;       // head (exp phase)
    int hf = lane >> 3;      // head owning this lane's feature pair (f/16)
    int f  = lane * 2;       // features f, f+1
    int start = rowptr[dst], end = rowptr[dst + 1];
    float adst = a_dst[dst * 8 + hj];

    float acc0 = 0.f, acc1 = 0.f, denl = 0.f;

    // prologue: first batch's src id + raw logit in flight
    int i = start + j;
    int s = (i < end) ? (int)ssrc[i] : -1;
    float ar = (s >= 0) ? a_src[s * 8 + hj] : 0.f;

    for (int base = start; base < end; base += 8) {
        // shuffle src ids FIRST and launch the 8 coalesced row-gathers immediately
        int sA[8];
#pragma unroll
        for (int j2 = 0; j2 < 8; j2++) sA[j2] = __shfl(s, j2 * 8);   // uniform lane -> readlane
        unsigned uA[8];
#pragma unroll
        for (int j2 = 0; j2 < 8; j2++)
            uA[j2] = (sA[j2] >= 0) ? *(const unsigned*)(Hbf + (size_t)sA[j2] * 128 + f) : 0u;

        // prefetch NEXT batch (overlaps with the gathers above + FMA below)
        int inext = base + 8 + j;
        int snext = (inext < end) ? (int)ssrc[inext] : -1;
        float anext = (snext >= 0) ? a_src[snext * 8 + hj] : 0.f;

        // exp + weight shuffle while row-gathers are in flight
        float w = (s >= 0) ? __expf(lrelu(ar + adst)) : 0.f;
        denl += w;
        float wA[8];
#pragma unroll
        for (int j2 = 0; j2 < 8; j2++) wA[j2] = __shfl(w, j2 * 8 + hf);   // bpermute

#pragma unroll
        for (int j2 = 0; j2 < 8; j2++) {
            acc0 += wA[j2] * __uint_as_float(uA[j2] << 16);
            acc1 += wA[j2] * __uint_as_float(uA[j2] & 0xffff0000u);
        }
        s = snext;
        ar = anext;
    }
    // reduce den over the 8 slots (stride-8 lanes share a head)
#pragma unroll
    for (int off = 8; off < 64; off <<= 1) denl += __shfl_xor(denl, off);
    float den = __shfl(denl, hf);
    float inv = 1.f / (den + 1e-16f);
    if (!MEAN) {
        *(float2*)(outbuf + (size_t)dst * 128 + f) = make_float2(acc0 * inv, acc1 * inv);
    } else {
        // head-mean: reduce features c=f&15 across the 8 heads (lanes sharing lane%8)
        float r0 = acc0 * inv, r1 = acc1 * inv;
#pragma unroll
        for (int off = 8; off < 64; off <<= 1) {
            r0 += __shfl_xor(r0, off);
            r1 += __shfl_xor(r1, off);
        }
        if (lane < 8)
            *(float2*)(outbuf + (size_t)dst * 16 + lane * 2) =
                make_float2(r0 * 0.125f, r1 * 0.125f);
    }
}

// ---------- batch-norm stats: two-stage deterministic reduction (NO atomics) ----------
template <int C>
__global__ __launch_bounds__(256) void stats_part_kernel(const float* __restrict__ X, int Nrows,
                                                         float* __restrict__ partial,
                                                         int rows_per_block) {
    constexpr int GSZ = 256 / C;
    __shared__ float ls[256], lq[256];
    int c = threadIdx.x % C;
    int g = threadIdx.x / C;
    long base = (long)blockIdx.x * rows_per_block;
    long endr = base + rows_per_block;
    if (endr > Nrows) endr = Nrows;
    float s = 0.f, q = 0.f;
    for (long r = base + g; r < endr; r += GSZ) {
        float v = X[r * C + c];
        s += v;
        q += v * v;
    }
    ls[threadIdx.x] = s;
    lq[threadIdx.x] = q;
    __syncthreads();
#pragma unroll
    for (int st = GSZ / 2; st > 0; st >>= 1) {
        if (g < st) {
            ls[threadIdx.x] += ls[threadIdx.x + st * C];
            lq[threadIdx.x] += lq[threadIdx.x + st * C];
        }
        __syncthreads();
    }
    if (g == 0) {
        partial[(size_t)blockIdx.x * (2 * C) + c] = ls[c];
        partial[(size_t)blockIdx.x * (2 * C) + C + c] = lq[c];
    }
}

// Stage 2: PARALLEL reduction of nblk partials (1024 threads, G groups per column).
template <int C>
__global__ __launch_bounds__(1024) void stats_final_kernel(const float* __restrict__ partial,
                                                           int nblk, float invN,
                                                           float* __restrict__ mu,
                                                           float* __restrict__ rsig) {
    constexpr int G = 1024 / C;
    __shared__ float ls[1024], lq[1024];
    int c = threadIdx.x % C;
    int g = threadIdx.x / C;
    float s = 0.f, q = 0.f;
    for (int b = g; b < nblk; b += G) {
        s += partial[(size_t)b * (2 * C) + c];
        q += partial[(size_t)b * (2 * C) + C + c];
    }
    ls[threadIdx.x] = s;
    lq[threadIdx.x] = q;
    __syncthreads();
#pragma unroll
    for (int st = G / 2; st > 0; st >>= 1) {
        if (g < st) {
            ls[threadIdx.x] += ls[threadIdx.x + st * C];
            lq[threadIdx.x] += lq[threadIdx.x + st * C];
        }
        __syncthreads();
    }
    if (g == 0) {
        float m_ = ls[c] * invN;
        float v = lq[c] * invN - m_ * m_;
        mu[c] = m_;
        rsig[c] = rsqrtf(v + BN_EPS);
    }
}

// ---------- final: BN(16) + logits = v @ Wc + bc ----------
__global__ void final_kernel(const float* __restrict__ out1,
                             const float* __restrict__ mu, const float* __restrict__ rsig,
                             const float* __restrict__ gamma, const float* __restrict__ beta,
                             const float* __restrict__ Wc, const float* __restrict__ bc,
                             float* __restrict__ out, int N) {
    int n = blockIdx.x * 256 + threadIdx.x;
    if (n >= N) return;
    float l0 = bc[0], l1 = bc[1];
#pragma unroll
    for (int c = 0; c < 16; c++) {
        float v = (out1[(size_t)n * 16 + c] - mu[c]) * rsig[c] * gamma[c] + beta[c];
        l0 += v * Wc[c * 2 + 0];
        l1 += v * Wc[c * 2 + 1];
    }
    out[(size_t)n * 2 + 0] = l0;
    out[(size_t)n * 2 + 1] = l1;
}

// ---------- launcher ----------
extern "C" void kernel_launch(void* const* d_in, const int* in_sizes, int n_in,
                              void* d_out, int out_size, void* d_ws, size_t ws_size,
                              hipStream_t stream) {
    const float* x   = (const float*)d_in[0];
    const int*   ei  = (const int*)d_in[1];
    const float* W0  = (const float*)d_in[2];
    const float* as0 = (const float*)d_in[3];
    const float* ad0 = (const float*)d_in[4];
    // d_in[5] = b0: cancelled exactly by the following batch-norm's mean subtraction
    const float* g0  = (const float*)d_in[6];
    const float* be0 = (const float*)d_in[7];
    const float* W1  = (const float*)d_in[8];
    const float* as1 = (const float*)d_in[9];
    const float* ad1 = (const float*)d_in[10];
    // d_in[11] = b1: cancelled by BN as well
    const float* g1  = (const float*)d_in[12];
    const float* be1 = (const float*)d_in[13];
    const float* Wc  = (const float*)d_in[14];
    const float* bc  = (const float*)d_in[15];
    float* out = (float*)d_out;

    int N = in_sizes[0] / 128;
    int E = in_sizes[1] / 2;
    int Etot = E + N;

    // workspace layout
    char* ws = (char*)d_ws;
    size_t off = 0;
    auto walloc = [&](size_t bytes) -> void* {
        void* p = ws + off;
        off += (bytes + 255) & ~(size_t)255;
        return p;
    };
    float*          B       = (float*)walloc((size_t)N * 128 * 4);
    unsigned short* Hbf     = (unsigned short*)walloc((size_t)N * 128 * 2);
    float*          a_src   = (float*)walloc((size_t)N * 8 * 4);
    float*          a_dst   = (float*)walloc((size_t)N * 8 * 4);
    float*          out1    = (float*)walloc((size_t)N * 16 * 4);
    int*            counts  = (int*)walloc((size_t)N * 4);
    int*            rowptr  = (int*)walloc((size_t)(N + 1) * 4);
    int*            rank    = (int*)walloc((size_t)Etot * 4);
    int*            csum    = (int*)walloc(64 * 4);
    unsigned short* ssrc    = (unsigned short*)walloc((size_t)Etot * 2);
    float*          partial = (float*)walloc((size_t)256 * 256 * 4);   // [256 blocks][2*128]
    float*          stats   = (float*)walloc(2 * 128 * 4);
    float*          Wt0     = (float*)walloc((size_t)128 * 128 * 4);
    float*          Wt1     = (float*)walloc((size_t)128 * 128 * 4);
    float* mu = stats, * rsig = stats + 128;

    dim3 b256(256);
    int gN64    = (N + 63) / 64;
    dim3 gGemm(gN64, 4);
    int gE      = (Etot + 255) / 256;
    int gAgg    = (N + 3) / 4;
    int nchunk  = (N + 1023) / 1024;
    const int SBLK = 256;
    int rpb = (N + SBLK - 1) / SBLK;

    // ---- W transposes (both layers, once) ----
    transpose_kernel<<<8, b256, 0, stream>>>(W0, W1, Wt0, Wt1);

    // ---- CSR build (once; same graph for both layers) ----
    hipMemsetAsync(counts, 0, (size_t)N * 4, stream);
    hist_kernel<<<gE, b256, 0, stream>>>(ei, E, Etot, counts, rank);
    chunksum_kernel<<<nchunk, b256, 0, stream>>>(counts, csum, N);
    chunkscan_kernel<<<1, 64, 0, stream>>>(csum, nchunk);
    scanfinal_kernel<<<nchunk, 1024, 0, stream>>>(counts, csum, rowptr, N);
    scatter_kernel<<<gE, b256, 0, stream>>>(ei, E, Etot, rowptr, rank, ssrc);

    // ---- layer 0 (att logits fused into gemm epilogue; no fp32 h0 materialized) ----
    gemm128<<<gGemm, b256, 0, stream>>>(x, Wt0, Hbf, as0, ad0, a_src, a_dst,
                                        nullptr, nullptr, nullptr, nullptr, N);
    agg_kernel<false><<<gAgg, b256, 0, stream>>>(rowptr, ssrc, a_src, a_dst, Hbf, B, N); // B = agg0
    stats_part_kernel<128><<<SBLK, b256, 0, stream>>>(B, N, partial, rpb);
    stats_final_kernel<128><<<1, 1024, 0, stream>>>(partial, SBLK, 1.0f / N, mu, rsig);

    // ---- layer 1 (BN+ELU fused into gemm X-load; att fused into epilogue) ----
    gemm128<<<gGemm, b256, 0, stream>>>(B, Wt1, Hbf, as1, ad1, a_src, a_dst,
                                        mu, rsig, g0, be0, N);
    agg_kernel<true><<<gAgg, b256, 0, stream>>>(rowptr, ssrc, a_src, a_dst, Hbf, out1, N); // out1 = head-mean(agg1)
    stats_part_kernel<16><<<SBLK, b256, 0, stream>>>(out1, N, partial, rpb);
    stats_final_kernel<16><<<1, 1024, 0, stream>>>(partial, SBLK, 1.0f / N, mu, rsig);
    final_kernel<<<(N + 255) / 256, b256, 0, stream>>>(out1, mu, rsig, g1, be1, Wc, bc, out, N);
}

// Round 8
// 369.100 us; speedup vs baseline: 1.3437x; 1.3437x over previous
//
#include <hip/hip_runtime.h>
#include <math.h>

#define NEG_SLOPE 0.2f
#define BN_EPS 1e-5f

typedef __attribute__((ext_vector_type(8))) short short8v;   // 8 bf16 (4 VGPRs)
typedef __attribute__((ext_vector_type(4))) float f32x4;     // MFMA accumulator

// ---------- helpers ----------

__device__ __forceinline__ void edge_sd(const int* __restrict__ ei, int E, int eid, int& s, int& d) {
    if (eid < E) { s = ei[eid]; d = ei[E + eid]; }
    else         { s = d = eid - E; }   // self-loops appended after the E real edges
}

__device__ __forceinline__ float lrelu(float v) { return v > 0.f ? v : NEG_SLOPE * v; }

// round-to-nearest-even fp32 -> bf16 bits
__device__ __forceinline__ unsigned short f2bf(float f) {
    unsigned u = __float_as_uint(f);
    u += 0x7fffu + ((u >> 16) & 1u);
    return (unsigned short)(u >> 16);
}
__device__ __forceinline__ float bfval(unsigned short u) {
    return __uint_as_float(((unsigned)u) << 16);
}

// ---------- W prep: transpose + hi/lo bf16 split: Wt[col][k], both layers (once) ----------
__global__ __launch_bounds__(256) void wsplit_kernel(const float* __restrict__ W0,
                                                     const float* __restrict__ W1,
                                                     unsigned short* __restrict__ H0,
                                                     unsigned short* __restrict__ L0,
                                                     unsigned short* __restrict__ H1,
                                                     unsigned short* __restrict__ L1) {
    int b = blockIdx.x;
    const float* S = (b & 4) ? W1 : W0;
    unsigned short* H = (b & 4) ? H1 : H0;
    unsigned short* L = (b & 4) ? L1 : L0;
    int part = b & 3;
    for (int i = threadIdx.x; i < 4096; i += 256) {
        int idx = part * 4096 + i;
        int k = idx >> 7, c = idx & 127;
        float v = S[idx];
        unsigned short h = f2bf(v);
        unsigned short l = f2bf(v - bfval(h));
        H[c * 128 + k] = h;
        L[c * 128 + k] = l;
    }
}

// ---------- GEMM: act(X)[N,128] @ W[128,128] via MFMA (bf16 hi/lo split, fp32-class accuracy) ----------
// fp32-VALU GEMMs plateaued at ~44us across 3 structures (MfmaUtil=0 every round).
// Now: v_mfma_f32_16x16x32_bf16, 3 MFMAs per tile (hi*hi + hi*lo + lo*hi; dropped lo*lo
// ~2^-16 rel). A-frags read directly from global (lane = row, 8 contiguous k as bf16
// hi/lo; BN+ELU applied in-register for layer 1). B-frags from pre-split transposed
// Wt[col][k] bf16 -> contiguous 16B per lane, L1-resident (16KB per k-chunk).
// C/D layout (HW-verified): col=lane&15, row=(lane>>4)*4+reg. Epilogue stages fp32 h
// in LDS -> exact att logits + coalesced bf16 shadow writes.
__global__ __launch_bounds__(256) void gemm128(const float* __restrict__ X,
                                               const unsigned short* __restrict__ Wthi,
                                               const unsigned short* __restrict__ Wtlo,
                                               unsigned short* __restrict__ Ybf,
                                               const float* __restrict__ att_s,
                                               const float* __restrict__ att_d,
                                               float* __restrict__ a_srcO,
                                               float* __restrict__ a_dstO,
                                               const float* __restrict__ bnmu,
                                               const float* __restrict__ bnrs,
                                               const float* __restrict__ gamma,
                                               const float* __restrict__ beta,
                                               int Nrows) {
    __shared__ float hs[64 * 128];     // 32 KB fp32 result staging
    int bm = blockIdx.x * 64;
    int tid = threadIdx.x;
    int w = tid >> 6, lane = tid & 63;
    int li = lane & 15, g = lane >> 4;
    int row = bm + w * 16 + li;        // this lane's A row
    bool rok = row < Nrows;
    const float* xp = X + (size_t)row * 128;

    f32x4 acc[8];
#pragma unroll
    for (int ct = 0; ct < 8; ct++) acc[ct] = (f32x4){0.f, 0.f, 0.f, 0.f};

#pragma unroll
    for (int kc = 0; kc < 4; kc++) {
        int kb = kc * 32 + g * 8;      // this lane's 8 contiguous k
        float xv[8];
        if (rok) {
            float4 x0 = *(const float4*)(xp + kb);
            float4 x1 = *(const float4*)(xp + kb + 4);
            xv[0] = x0.x; xv[1] = x0.y; xv[2] = x0.z; xv[3] = x0.w;
            xv[4] = x1.x; xv[5] = x1.y; xv[6] = x1.z; xv[7] = x1.w;
        } else {
#pragma unroll
            for (int e = 0; e < 8; e++) xv[e] = 0.f;
        }
        if (bnmu != nullptr) {         // layer-1: BN+ELU on the fly
            float mv[8], rv[8], gv[8], bv[8];
            *(float4*)(mv)     = *(const float4*)(bnmu + kb);
            *(float4*)(mv + 4) = *(const float4*)(bnmu + kb + 4);
            *(float4*)(rv)     = *(const float4*)(bnrs + kb);
            *(float4*)(rv + 4) = *(const float4*)(bnrs + kb + 4);
            *(float4*)(gv)     = *(const float4*)(gamma + kb);
            *(float4*)(gv + 4) = *(const float4*)(gamma + kb + 4);
            *(float4*)(bv)     = *(const float4*)(beta + kb);
            *(float4*)(bv + 4) = *(const float4*)(beta + kb + 4);
#pragma unroll
            for (int e = 0; e < 8; e++) {
                float t = (xv[e] - mv[e]) * rv[e] * gv[e] + bv[e];
                xv[e] = t > 0.f ? t : expm1f(t);
            }
        }
        short8v ah, al;
#pragma unroll
        for (int e = 0; e < 8; e++) {
            unsigned short hb = f2bf(xv[e]);
            ah[e] = (short)hb;
            al[e] = (short)f2bf(xv[e] - bfval(hb));
        }
        const unsigned short* wb  = Wthi + (size_t)li * 128 + kb;
        const unsigned short* wlb = Wtlo + (size_t)li * 128 + kb;
#pragma unroll
        for (int ct = 0; ct < 8; ct++) {
            short8v bh = *(const short8v*)(wb  + ct * 2048);   // (ct*16+li) row of Wt
            short8v bl = *(const short8v*)(wlb + ct * 2048);
            acc[ct] = __builtin_amdgcn_mfma_f32_16x16x32_bf16(ah, bh, acc[ct], 0, 0, 0);
            acc[ct] = __builtin_amdgcn_mfma_f32_16x16x32_bf16(ah, bl, acc[ct], 0, 0, 0);
            acc[ct] = __builtin_amdgcn_mfma_f32_16x16x32_bf16(al, bh, acc[ct], 0, 0, 0);
        }
    }

    // ---- stage fp32 h to LDS (D layout: col=lane&15, row=(lane>>4)*4+reg) ----
#pragma unroll
    for (int ct = 0; ct < 8; ct++)
#pragma unroll
        for (int r = 0; r < 4; r++)
            hs[(w * 16 + g * 4 + r) * 128 + ct * 16 + li] = acc[ct][r];
    __syncthreads();

    // ---- attention logits from fp32 h (512 (row,head) pairs, 2 per thread) ----
#pragma unroll
    for (int p0 = 0; p0 < 2; p0++) {
        int p = tid + p0 * 256;
        int r = p >> 3, hh = p & 7;
        if (bm + r < Nrows) {
            const float4* hp4 = (const float4*)(hs + r * 128 + hh * 16);
            const float4* as4 = (const float4*)(att_s + hh * 16);
            const float4* ad4 = (const float4*)(att_d + hh * 16);
            float ss = 0.f, sd = 0.f;
#pragma unroll
            for (int q = 0; q < 4; q++) {
                float4 v = hp4[q], s4 = as4[q], d4 = ad4[q];
                ss += v.x * s4.x + v.y * s4.y + v.z * s4.z + v.w * s4.w;
                sd += v.x * d4.x + v.y * d4.y + v.z * d4.z + v.w * d4.w;
            }
            a_srcO[(size_t)(bm + r) * 8 + hh] = ss;
            a_dstO[(size_t)(bm + r) * 8 + hh] = sd;
        }
    }

    // ---- bf16 shadow, coalesced (thread -> 32 consecutive cols of one row) ----
    {
        int r = tid >> 2, seg = tid & 3;
        if (bm + r < Nrows) {
            const float* hp = hs + r * 128 + seg * 32;
#pragma unroll
            for (int q = 0; q < 4; q++) {
                float4 a = *(const float4*)(hp + q * 8);
                float4 b = *(const float4*)(hp + q * 8 + 4);
                uint4 o;
                o.x = (unsigned)f2bf(a.x) | ((unsigned)f2bf(a.y) << 16);
                o.y = (unsigned)f2bf(a.z) | ((unsigned)f2bf(a.w) << 16);
                o.z = (unsigned)f2bf(b.x) | ((unsigned)f2bf(b.y) << 16);
                o.w = (unsigned)f2bf(b.z) | ((unsigned)f2bf(b.w) << 16);
                *(uint4*)(Ybf + (size_t)(bm + r) * 128 + seg * 32 + q * 8) = o;
            }
        }
    }
}

// ---------- CSR build: histogram of dst + within-bucket rank (atomic return value) ----------
__global__ void hist_kernel(const int* __restrict__ ei, int E, int Etot,
                            int* __restrict__ counts, int* __restrict__ rank) {
    int eid = blockIdx.x * 256 + threadIdx.x;
    if (eid >= Etot) return;
    int s, d;
    edge_sd(ei, E, eid, s, d);
    rank[eid] = atomicAdd(&counts[d], 1);
}

// ---------- CSR build: parallel 3-stage exclusive scan ----------
__global__ __launch_bounds__(256) void chunksum_kernel(const int* __restrict__ counts,
                                                       int* __restrict__ csum, int N) {
    __shared__ int red[256];
    int base = blockIdx.x * 1024;
    int s = 0;
    for (int i = threadIdx.x; i < 1024; i += 256) {
        int idx = base + i;
        s += (idx < N) ? counts[idx] : 0;
    }
    red[threadIdx.x] = s;
    __syncthreads();
#pragma unroll
    for (int st = 128; st > 0; st >>= 1) {
        if (threadIdx.x < st) red[threadIdx.x] += red[threadIdx.x + st];
        __syncthreads();
    }
    if (threadIdx.x == 0) csum[blockIdx.x] = red[0];
}

__global__ void chunkscan_kernel(int* __restrict__ csum, int nchunk) {
    int lane = threadIdx.x;
    int v = (lane < nchunk) ? csum[lane] : 0;
    int incl = v;
#pragma unroll
    for (int off = 1; off < 64; off <<= 1) {
        int t = __shfl_up(incl, off);
        if (lane >= off) incl += t;
    }
    if (lane < nchunk) csum[lane] = incl - v;
}

__global__ __launch_bounds__(1024) void scanfinal_kernel(const int* __restrict__ counts,
                                                         const int* __restrict__ csum,
                                                         int* __restrict__ rowptr, int N) {
    __shared__ int wsum[16], woff_s[16];
    int tid = threadIdx.x, lane = tid & 63, wid = tid >> 6;
    int idx = blockIdx.x * 1024 + tid;
    int v = (idx < N) ? counts[idx] : 0;
    int incl = v;
#pragma unroll
    for (int off = 1; off < 64; off <<= 1) {
        int t = __shfl_up(incl, off);
        if (lane >= off) incl += t;
    }
    if (lane == 63) wsum[wid] = incl;
    __syncthreads();
    if (wid == 0 && lane < 16) {
        int w = wsum[lane], iw = w;
#pragma unroll
        for (int off = 1; off < 16; off <<= 1) {
            int t = __shfl_up(iw, off);
            if (lane >= off) iw += t;
        }
        woff_s[lane] = iw - w;
    }
    __syncthreads();
    if (idx < N) rowptr[idx + 1] = csum[blockIdx.x] + woff_s[wid] + incl;
    if (blockIdx.x == 0 && tid == 0) rowptr[0] = 0;
}

// ---------- CSR build: scatter src ids (NO atomics; rank precomputed in hist) ----------
__global__ void scatter_kernel(const int* __restrict__ ei, int E, int Etot,
                               const int* __restrict__ rowptr, const int* __restrict__ rank,
                               unsigned short* __restrict__ ssrc) {
    int eid = blockIdx.x * 256 + threadIdx.x;
    if (eid >= Etot) return;
    int s, d;
    edge_sd(ei, E, eid, s, d);
    ssrc[rowptr[d] + rank[eid]] = (unsigned short)s;
}

// ---------- fused softmax + aggregation: one wave per dst, 8 edges per iteration ----------
// Software-pipelined: row-gathers issued before exp/bpermute; next batch's ssrc/a_src
// prefetched during the FMA phase (breaks the serial load->exp->shuffle->load chain).
// MEAN=false: writes full [dst,128]. MEAN=true: head-mean fused -> writes [dst,16].
template <bool MEAN>
__global__ __launch_bounds__(256) void agg_kernel(const int* __restrict__ rowptr,
                                                  const unsigned short* __restrict__ ssrc,
                                                  const float* __restrict__ a_src,
                                                  const float* __restrict__ a_dst,
                                                  const unsigned short* __restrict__ Hbf,
                                                  float* __restrict__ outbuf, int N) {
    int wid = threadIdx.x >> 6;
    int dst = blockIdx.x * 4 + wid;
    if (dst >= N) return;
    int lane = threadIdx.x & 63;
    int j  = lane >> 3;      // edge slot 0..7 (exp phase)
    int hj = lane & 7;       // head (exp phase)
    int hf = lane >> 3;      // head owning this lane's feature pair (f/16)
    int f  = lane * 2;       // features f, f+1
    int start = rowptr[dst], end = rowptr[dst + 1];
    float adst = a_dst[dst * 8 + hj];

    float acc0 = 0.f, acc1 = 0.f, denl = 0.f;

    // prologue: first batch's src id + raw logit in flight
    int i = start + j;
    int s = (i < end) ? (int)ssrc[i] : -1;
    float ar = (s >= 0) ? a_src[s * 8 + hj] : 0.f;

    for (int base = start; base < end; base += 8) {
        // shuffle src ids FIRST and launch the 8 coalesced row-gathers immediately
        int sA[8];
#pragma unroll
        for (int j2 = 0; j2 < 8; j2++) sA[j2] = __shfl(s, j2 * 8);   // uniform lane -> readlane
        unsigned uA[8];
#pragma unroll
        for (int j2 = 0; j2 < 8; j2++)
            uA[j2] = (sA[j2] >= 0) ? *(const unsigned*)(Hbf + (size_t)sA[j2] * 128 + f) : 0u;

        // prefetch NEXT batch (overlaps with the gathers above + FMA below)
        int inext = base + 8 + j;
        int snext = (inext < end) ? (int)ssrc[inext] : -1;
        float anext = (snext >= 0) ? a_src[snext * 8 + hj] : 0.f;

        // exp + weight shuffle while row-gathers are in flight
        float w = (s >= 0) ? __expf(lrelu(ar + adst)) : 0.f;
        denl += w;
        float wA[8];
#pragma unroll
        for (int j2 = 0; j2 < 8; j2++) wA[j2] = __shfl(w, j2 * 8 + hf);   // bpermute

#pragma unroll
        for (int j2 = 0; j2 < 8; j2++) {
            acc0 += wA[j2] * __uint_as_float(uA[j2] << 16);
            acc1 += wA[j2] * __uint_as_float(uA[j2] & 0xffff0000u);
        }
        s = snext;
        ar = anext;
    }
    // reduce den over the 8 slots (stride-8 lanes share a head)
#pragma unroll
    for (int off = 8; off < 64; off <<= 1) denl += __shfl_xor(denl, off);
    float den = __shfl(denl, hf);
    float inv = 1.f / (den + 1e-16f);
    if (!MEAN) {
        *(float2*)(outbuf + (size_t)dst * 128 + f) = make_float2(acc0 * inv, acc1 * inv);
    } else {
        // head-mean: reduce features c=f&15 across the 8 heads (lanes sharing lane%8)
        float r0 = acc0 * inv, r1 = acc1 * inv;
#pragma unroll
        for (int off = 8; off < 64; off <<= 1) {
            r0 += __shfl_xor(r0, off);
            r1 += __shfl_xor(r1, off);
        }
        if (lane < 8)
            *(float2*)(outbuf + (size_t)dst * 16 + lane * 2) =
                make_float2(r0 * 0.125f, r1 * 0.125f);
    }
}

// ---------- batch-norm stats: two-stage deterministic reduction (NO atomics) ----------
template <int C>
__global__ __launch_bounds__(256) void stats_part_kernel(const float* __restrict__ X, int Nrows,
                                                         float* __restrict__ partial,
                                                         int rows_per_block) {
    constexpr int GSZ = 256 / C;
    __shared__ float ls[256], lq[256];
    int c = threadIdx.x % C;
    int g = threadIdx.x / C;
    long base = (long)blockIdx.x * rows_per_block;
    long endr = base + rows_per_block;
    if (endr > Nrows) endr = Nrows;
    float s = 0.f, q = 0.f;
    for (long r = base + g; r < endr; r += GSZ) {
        float v = X[r * C + c];
        s += v;
        q += v * v;
    }
    ls[threadIdx.x] = s;
    lq[threadIdx.x] = q;
    __syncthreads();
#pragma unroll
    for (int st = GSZ / 2; st > 0; st >>= 1) {
        if (g < st) {
            ls[threadIdx.x] += ls[threadIdx.x + st * C];
            lq[threadIdx.x] += lq[threadIdx.x + st * C];
        }
        __syncthreads();
    }
    if (g == 0) {
        partial[(size_t)blockIdx.x * (2 * C) + c] = ls[c];
        partial[(size_t)blockIdx.x * (2 * C) + C + c] = lq[c];
    }
}

// Stage 2: PARALLEL reduction of nblk partials (1024 threads, G groups per column).
template <int C>
__global__ __launch_bounds__(1024) void stats_final_kernel(const float* __restrict__ partial,
                                                           int nblk, float invN,
                                                           float* __restrict__ mu,
                                                           float* __restrict__ rsig) {
    constexpr int G = 1024 / C;
    __shared__ float ls[1024], lq[1024];
    int c = threadIdx.x % C;
    int g = threadIdx.x / C;
    float s = 0.f, q = 0.f;
    for (int b = g; b < nblk; b += G) {
        s += partial[(size_t)b * (2 * C) + c];
        q += partial[(size_t)b * (2 * C) + C + c];
    }
    ls[threadIdx.x] = s;
    lq[threadIdx.x] = q;
    __syncthreads();
#pragma unroll
    for (int st = G / 2; st > 0; st >>= 1) {
        if (g < st) {
            ls[threadIdx.x] += ls[threadIdx.x + st * C];
            lq[threadIdx.x] += lq[threadIdx.x + st * C];
        }
        __syncthreads();
    }
    if (g == 0) {
        float m_ = ls[c] * invN;
        float v = lq[c] * invN - m_ * m_;
        mu[c] = m_;
        rsig[c] = rsqrtf(v + BN_EPS);
    }
}

// ---------- final: BN(16) + logits = v @ Wc + bc ----------
__global__ void final_kernel(const float* __restrict__ out1,
                             const float* __restrict__ mu, const float* __restrict__ rsig,
                             const float* __restrict__ gamma, const float* __restrict__ beta,
                             const float* __restrict__ Wc, const float* __restrict__ bc,
                             float* __restrict__ out, int N) {
    int n = blockIdx.x * 256 + threadIdx.x;
    if (n >= N) return;
    float l0 = bc[0], l1 = bc[1];
#pragma unroll
    for (int c = 0; c < 16; c++) {
        float v = (out1[(size_t)n * 16 + c] - mu[c]) * rsig[c] * gamma[c] + beta[c];
        l0 += v * Wc[c * 2 + 0];
        l1 += v * Wc[c * 2 + 1];
    }
    out[(size_t)n * 2 + 0] = l0;
    out[(size_t)n * 2 + 1] = l1;
}

// ---------- launcher ----------
extern "C" void kernel_launch(void* const* d_in, const int* in_sizes, int n_in,
                              void* d_out, int out_size, void* d_ws, size_t ws_size,
                              hipStream_t stream) {
    const float* x   = (const float*)d_in[0];
    const int*   ei  = (const int*)d_in[1];
    const float* W0  = (const float*)d_in[2];
    const float* as0 = (const float*)d_in[3];
    const float* ad0 = (const float*)d_in[4];
    // d_in[5] = b0: cancelled exactly by the following batch-norm's mean subtraction
    const float* g0  = (const float*)d_in[6];
    const float* be0 = (const float*)d_in[7];
    const float* W1  = (const float*)d_in[8];
    const float* as1 = (const float*)d_in[9];
    const float* ad1 = (const float*)d_in[10];
    // d_in[11] = b1: cancelled by BN as well
    const float* g1  = (const float*)d_in[12];
    const float* be1 = (const float*)d_in[13];
    const float* Wc  = (const float*)d_in[14];
    const float* bc  = (const float*)d_in[15];
    float* out = (float*)d_out;

    int N = in_sizes[0] / 128;
    int E = in_sizes[1] / 2;
    int Etot = E + N;

    // workspace layout
    char* ws = (char*)d_ws;
    size_t off = 0;
    auto walloc = [&](size_t bytes) -> void* {
        void* p = ws + off;
        off += (bytes + 255) & ~(size_t)255;
        return p;
    };
    float*          B       = (float*)walloc((size_t)N * 128 * 4);
    unsigned short* Hbf     = (unsigned short*)walloc((size_t)N * 128 * 2);
    float*          a_src   = (float*)walloc((size_t)N * 8 * 4);
    float*          a_dst   = (float*)walloc((size_t)N * 8 * 4);
    float*          out1    = (float*)walloc((size_t)N * 16 * 4);
    int*            counts  = (int*)walloc((size_t)N * 4);
    int*            rowptr  = (int*)walloc((size_t)(N + 1) * 4);
    int*            rank    = (int*)walloc((size_t)Etot * 4);
    int*            csum    = (int*)walloc(64 * 4);
    unsigned short* ssrc    = (unsigned short*)walloc((size_t)Etot * 2);
    float*          partial = (float*)walloc((size_t)256 * 256 * 4);   // [256 blocks][2*128]
    float*          stats   = (float*)walloc(2 * 128 * 4);
    unsigned short* Whi0    = (unsigned short*)walloc((size_t)128 * 128 * 2);
    unsigned short* Wlo0    = (unsigned short*)walloc((size_t)128 * 128 * 2);
    unsigned short* Whi1    = (unsigned short*)walloc((size_t)128 * 128 * 2);
    unsigned short* Wlo1    = (unsigned short*)walloc((size_t)128 * 128 * 2);
    float* mu = stats, * rsig = stats + 128;

    dim3 b256(256);
    int gN64    = (N + 63) / 64;
    int gE      = (Etot + 255) / 256;
    int gAgg    = (N + 3) / 4;
    int nchunk  = (N + 1023) / 1024;
    const int SBLK = 256;
    int rpb = (N + SBLK - 1) / SBLK;

    // ---- W transpose + hi/lo split (both layers, once) ----
    wsplit_kernel<<<8, b256, 0, stream>>>(W0, W1, Whi0, Wlo0, Whi1, Wlo1);

    // ---- CSR build (once; same graph for both layers) ----
    hipMemsetAsync(counts, 0, (size_t)N * 4, stream);
    hist_kernel<<<gE, b256, 0, stream>>>(ei, E, Etot, counts, rank);
    chunksum_kernel<<<nchunk, b256, 0, stream>>>(counts, csum, N);
    chunkscan_kernel<<<1, 64, 0, stream>>>(csum, nchunk);
    scanfinal_kernel<<<nchunk, 1024, 0, stream>>>(counts, csum, rowptr, N);
    scatter_kernel<<<gE, b256, 0, stream>>>(ei, E, Etot, rowptr, rank, ssrc);

    // ---- layer 0 (att logits fused into gemm epilogue; no fp32 h0 materialized) ----
    gemm128<<<gN64, b256, 0, stream>>>(x, Whi0, Wlo0, Hbf, as0, ad0, a_src, a_dst,
                                       nullptr, nullptr, nullptr, nullptr, N);
    agg_kernel<false><<<gAgg, b256, 0, stream>>>(rowptr, ssrc, a_src, a_dst, Hbf, B, N); // B = agg0
    stats_part_kernel<128><<<SBLK, b256, 0, stream>>>(B, N, partial, rpb);
    stats_final_kernel<128><<<1, 1024, 0, stream>>>(partial, SBLK, 1.0f / N, mu, rsig);

    // ---- layer 1 (BN+ELU fused into gemm A-load; att fused into epilogue) ----
    gemm128<<<gN64, b256, 0, stream>>>(B, Whi1, Wlo1, Hbf, as1, ad1, a_src, a_dst,
                                       mu, rsig, g0, be0, N);
    agg_kernel<true><<<gAgg, b256, 0, stream>>>(rowptr, ssrc, a_src, a_dst, Hbf, out1, N); // out1 = head-mean(agg1)
    stats_part_kernel<16><<<SBLK, b256, 0, stream>>>(out1, N, partial, rpb);
    stats_final_kernel<16><<<1, 1024, 0, stream>>>(partial, SBLK, 1.0f / N, mu, rsig);
    final_kernel<<<(N + 255) / 256, b256, 0, stream>>>(out1, mu, rsig, g1, be1, Wc, bc, out, N);
}